// Round 18
// baseline (359.455 us; speedup 1.0000x reference)
//
#include <hip/hip_runtime.h>

// CIN fused kernel, round 16: r15 + wave phase-staggered step order.
// r15 (174us dispatch, MfmaUtil 57.5%, WRITE 32B no-spill) confirmed the
// L1-BW model: LDS B-sharing via T14 reg-staging works. Residual: 3600
// cyc/iter vs 2048 MFMA floor; gap 1550 = LDS read time (128KB/iter @
// ~85B/cyc) fully SERIAL with MFMA. Cause: per-iter barrier re-converges
// all waves onto the identical step sequence -> both waves of a SIMD issue
// ds_read bursts simultaneously and stall on lgkmcnt together. Register
// prefetch impossible (252/256 unified regs).
// Fix (0 regs, 0 sync change): half the waves run steps 0,1,2,3; half run
// 2,3,0,1. Accumulation commutes; liveness guards are per-step; barriers
// unchanged. Each SIMD's wave pair is then always on DIFFERENT steps: one
// wave's 256-cyc MFMA run hides the other's ds_read latency. Phase =
// (wave ^ (wave>>2)) & 1 -> opposite phases within a SIMD pair under both
// w%4 and w/2 wave->SIMD mappings. STAGE_WRITE stays 3 compute-steps after
// STAGE_LOAD in both orders.
// Geometry/structure otherwise byte-identical to r15: NB=32, 512 thr,
// wave = 2m x 4n, acc[2][4]=128 AGPR, hreg resident, premask fprep,
// one __syncthreads per iter (zero drain), LDS 147.9KB, 1 block/CU.

#define F0N 39
#define NB  32                                // batches per block
#define NC16 156                              // K/16 per layer
#define LAYER_HALVES (NC16 * 4 * 64 * 8)      // 319488 f16 per layer
#define IHALFS 8192                           // halfs per i-panel (4 steps x 4nt x 64 x 8)

typedef _Float16 half8 __attribute__((ext_vector_type(8)));
typedef float f32x16 __attribute__((ext_vector_type(16)));

// ---- prep: swizzle filters into 32x32x16 B-fragment order, f16 ----
// fprep[l][c16][nt][lane][reg] = F_l[row(kg), nt*32 + (lane&31)],
// kg = c16*16 + (lane>>5)*8 + reg.
// Layer 0 PREMASKED: row = i*39+j (i=kg>>6, j=kg&63); value = 2*f0[row,n]
// if (j<39 && j>i) else 0 (triu mask + 2.0 scale baked in; verified).
__global__ void prep_kernel(const float* __restrict__ f0,
                            const float* __restrict__ f1,
                            const float* __restrict__ f2,
                            _Float16* __restrict__ fprep) {
    int blk  = blockIdx.x;            // l*NC16 + c16
    int l    = blk / NC16;
    int c16  = blk - l * NC16;
    int t    = threadIdx.x;
    int nt   = t >> 6;
    int lane = t & 63;
    int hf   = lane >> 5;
    int n    = nt * 32 + (lane & 31);
    const float* f = (l == 0) ? f0 : ((l == 1) ? f1 : f2);
    half8 v;
    #pragma unroll
    for (int reg = 0; reg < 8; ++reg) {
        int kg = c16 * 16 + hf * 8 + reg;
        float x;
        if (l == 0) {
            int fi = kg >> 6, fj = kg & 63;
            x = (fj < F0N && fj > fi) ? 2.0f * f[(fi * F0N + fj) * 128 + n] : 0.0f;
        } else {
            x = f[(size_t)kg * 128 + n];
        }
        v[reg] = (_Float16)x;
    }
    *(half8*)&fprep[(size_t)l * LAYER_HALVES + (((c16 * 4 + nt) * 64 + lane) << 3)] = v;
}

// One K=16 step (Q literal): Bf from LDS (lane-contiguous 16B, conflict-
// free), resident hreg, 8 MFMAs.
#define FULL_STEP_LS(Q)                                                       \
    do {                                                                      \
        half8 Bf[4];                                                          \
        _Pragma("unroll")                                                     \
        for (int nt = 0; nt < 4; ++nt)                                        \
            Bf[nt] = *(const half8*)&bcur[(((Q) * 4 + nt) * 64 + lane) << 3]; \
        half8 Af[2];                                                          \
        _Pragma("unroll")                                                     \
        for (int mt = 0; mt < 2; ++mt) Af[mt] = hreg[mt][(Q)] * xv2[mt];      \
        _Pragma("unroll")                                                     \
        for (int mt = 0; mt < 2; ++mt)                                        \
            _Pragma("unroll")                                                 \
            for (int nt = 0; nt < 4; ++nt)                                    \
                acc[mt][nt] = __builtin_amdgcn_mfma_f32_32x32x16_f16(         \
                    Af[mt], Bf[nt], acc[mt][nt], 0, 0, 0);                    \
    } while (0)

// issue global loads of panel IP into registers (consumed by STAGE_WRITE)
#define STAGE_LOAD(IP)                                                        \
    do {                                                                      \
        const uint4* g = (const uint4*)(fpl + (size_t)(IP) * IHALFS);         \
        s0 = g[t];                                                            \
        s1 = g[t + 512];                                                      \
    } while (0)

// write staged registers into LDS buffer (lane-contiguous 16B, no conflict)
#define STAGE_WRITE(BUFP)                                                     \
    do {                                                                      \
        ((uint4*)(BUFP))[t]       = s0;                                       \
        ((uint4*)(BUFP))[t + 512] = s1;                                       \
    } while (0)

__global__ __launch_bounds__(512, 2) void cin_mfma(
    const float* __restrict__ xin,     // (B, 624) fp32
    const _Float16* __restrict__ fprep,
    const float* __restrict__ wnn,     // (256)
    const float* __restrict__ bnn,     // (1)
    float* __restrict__ out)           // (B)
{
    __shared__ _Float16 hT[NB * 16 * 72] __attribute__((aligned(16)));  // [nb][d][j pad72]
    __shared__ _Float16 xs[NB * 16 * 40] __attribute__((aligned(16)));  // [nb][d][i pad40]
    __shared__ _Float16 bst[2][IHALFS] __attribute__((aligned(16)));    // B i-panel dbuf
    __shared__ float outacc[NB];

    const int t     = threadIdx.x;
    const int wave  = t >> 6;
    const int lane  = t & 63;
    const int hf    = lane >> 5;     // k-half within 16-chunk
    const int lane5 = lane & 31;
    const int dl    = lane & 15;     // d for A-side
    const int bt    = lane5 >> 4;    // A-side batch within 32-row tile
    const int wb0   = wave * 4;      // wave's first batch (local, 0..28)
    const int b0    = blockIdx.x * NB;
    // step-order phase: opposite within a SIMD wave-pair under both w%4
    // and w/2 wave->SIMD mappings.
    const bool phaseA = (((wave ^ (wave >> 2)) & 1) == 0);

    // zero hT (j-pad must be 0: layer-0 h-runs read j up to 63)
    for (int u = t; u < NB * 16 * 72 / 8; u += 512) ((uint4*)hT)[u] = uint4{0, 0, 0, 0};
    if (t < NB) outacc[t] = 0.0f;
    __syncthreads();

    // stage x0 -> hT (layer-0 hidden, [nb][d][j=i]) and xs ([nb][d][i])
    for (int u = t; u < NB * F0N; u += 512) {
        int nb = u / F0N;
        int i  = u - nb * F0N;
        const float* src = xin + (size_t)(b0 + nb) * 624 + i * 16;
        #pragma unroll
        for (int q = 0; q < 4; ++q) {
            float4 v = *(const float4*)(src + q * 4);
            int d = q * 4;
            hT[(nb * 16 + d + 0) * 72 + i] = (_Float16)v.x;
            hT[(nb * 16 + d + 1) * 72 + i] = (_Float16)v.y;
            hT[(nb * 16 + d + 2) * 72 + i] = (_Float16)v.z;
            hT[(nb * 16 + d + 3) * 72 + i] = (_Float16)v.w;
            xs[(nb * 16 + d + 0) * 40 + i] = (_Float16)v.x;
            xs[(nb * 16 + d + 1) * 40 + i] = (_Float16)v.y;
            xs[(nb * 16 + d + 2) * 40 + i] = (_Float16)v.z;
            xs[(nb * 16 + d + 3) * 40 + i] = (_Float16)v.w;
        }
    }
    __syncthreads();

    for (int layer = 0; layer < 3; ++layer) {
        const _Float16* fpl = fprep + (size_t)layer * LAYER_HALVES;
        uint4 s0, s1;

        // prologue: issue panel-0 loads (overlap with hreg ds_reads)
        STAGE_LOAD(0);

        // lane's A rows: batch wb0 + mt*2 + bt, d = dl; 4 half8 per batch.
        half8 hreg[2][4];
        #pragma unroll
        for (int mt = 0; mt < 2; ++mt) {
            int base = ((wb0 + mt * 2 + bt) * 16 + dl) * 72 + hf * 8;
            #pragma unroll
            for (int r = 0; r < 4; ++r)
                hreg[mt][r] = *(const half8*)&hT[base + r * 16];
        }
        __syncthreads();   // h-regs loaded (epilogue of prev layer done)

        STAGE_WRITE(bst[0]);   // panel 0 -> buf0 (waits its loads)
        __syncthreads();       // buf0 visible to all waves

        f32x16 acc[2][4];
        #pragma unroll
        for (int mt = 0; mt < 2; ++mt)
            #pragma unroll
            for (int nt = 0; nt < 4; ++nt)
                #pragma unroll
                for (int e = 0; e < 16; ++e) acc[mt][nt][e] = 0.0f;

        const int xrow0 = ((wb0 + bt) * 16 + dl) * 40;
        const int xrow1 = ((wb0 + 2 + bt) * 16 + dl) * 40;

        if (layer == 0) {
            // Premasked sparse: q0 live i<15, q1 live i<31, q2 live i<38,
            // q3 dead. 38 iterations. Step order phase-staggered.
            _Float16 xv2[2];
            for (int i = 0; i < 38; ++i) {
                const _Float16* bcur = bst[i & 1];
                _Float16* bnxt = bst[(i & 1) ^ 1];
                if (i < 37) STAGE_LOAD(i + 1);      // issue early
                xv2[0] = xs[xrow0 + i];
                xv2[1] = xs[xrow1 + i];
                if (phaseA) {
                    if (i < 15) FULL_STEP_LS(0);
                    if (i < 31) FULL_STEP_LS(1);
                    if (i < 37) STAGE_WRITE(bnxt);  // write late (loads landed)
                    FULL_STEP_LS(2);
                } else {
                    FULL_STEP_LS(2);
                    if (i < 15) FULL_STEP_LS(0);
                    if (i < 37) STAGE_WRITE(bnxt);
                    if (i < 31) FULL_STEP_LS(1);
                }
                __syncthreads();                    // buf swap; zero drain
            }
        } else {
            _Float16 xv2[2];
            for (int i = 0; i < F0N; ++i) {
                const _Float16* bcur = bst[i & 1];
                _Float16* bnxt = bst[(i & 1) ^ 1];
                if (i < F0N - 1) STAGE_LOAD(i + 1); // issue early
                xv2[0] = xs[xrow0 + i];
                xv2[1] = xs[xrow1 + i];
                if (phaseA) {
                    FULL_STEP_LS(0);
                    FULL_STEP_LS(1);
                    FULL_STEP_LS(2);
                    if (i < F0N - 1) STAGE_WRITE(bnxt);
                    FULL_STEP_LS(3);
                } else {
                    FULL_STEP_LS(2);
                    FULL_STEP_LS(3);
                    FULL_STEP_LS(0);
                    if (i < F0N - 1) STAGE_WRITE(bnxt);
                    FULL_STEP_LS(1);
                }
                __syncthreads();                    // buf swap; zero drain
            }
        }

        // ---- epilogue ----
        // C/D layout: col n = nt*32 + lane5; row = (reg&3) + 8*(reg>>2) + 4*hf;
        // batch_in_tile = reg>>3, d = (reg&3) + 8*((reg>>2)&1) + 4*hf.
        const int catbase = (layer == 2) ? 128 : ((layer == 0) ? -64 : 0);
        #pragma unroll
        for (int mt = 0; mt < 2; ++mt) {
            const int nb0 = wb0 + mt * 2;
            float cm0 = 0.0f, cm1 = 0.0f;
            #pragma unroll
            for (int nt = 0; nt < 4; ++nt) {
                float r[16];
                #pragma unroll
                for (int reg = 0; reg < 16; ++reg)
                    r[reg] = fmaxf(acc[mt][nt][reg], 0.0f);
                if (layer < 2 && nt < 2) {         // next hidden: cols 0..63
                    const int j = nt * 32 + lane5;
                    #pragma unroll
                    for (int reg = 0; reg < 16; ++reg) {
                        int nb = nb0 + (reg >> 3);
                        int d  = (reg & 3) + 8 * ((reg >> 2) & 1) + 4 * hf;
                        hT[(nb * 16 + d) * 72 + j] = (_Float16)r[reg];
                    }
                }
                if (layer == 2 || nt >= 2) {       // direct-out readout
                    const float w = 1.0f + wnn[catbase + nt * 32 + lane5];
                    float s0r = ((r[0] + r[1]) + (r[2] + r[3])) +
                                ((r[4] + r[5]) + (r[6] + r[7]));
                    float s1r = ((r[8] + r[9]) + (r[10] + r[11])) +
                                ((r[12] + r[13]) + (r[14] + r[15]));
                    s0r += __shfl_xor(s0r, 32, 64);  // combine hf halves
                    s1r += __shfl_xor(s1r, 32, 64);
                    cm0 = fmaf(s0r, w, cm0);
                    cm1 = fmaf(s1r, w, cm1);
                }
            }
            #pragma unroll
            for (int sh = 16; sh >= 1; sh >>= 1) {
                cm0 += __shfl_xor(cm0, sh, 64);
                cm1 += __shfl_xor(cm1, sh, 64);
            }
            if (lane == 0) {
                atomicAdd(&outacc[nb0], cm0);
                atomicAdd(&outacc[nb0 + 1], cm1);
            }
        }
        __syncthreads();   // hT(next hidden) + outacc visible
    }

    if (t < NB) out[b0 + t] = outacc[t] + bnn[0];
}

extern "C" void kernel_launch(void* const* d_in, const int* in_sizes, int n_in,
                              void* d_out, int out_size, void* d_ws, size_t ws_size,
                              hipStream_t stream) {
    const float* xin = (const float*)d_in[0];
    const float* f0g = (const float*)d_in[1];
    const float* f1g = (const float*)d_in[2];
    const float* f2g = (const float*)d_in[3];
    const float* wnn = (const float*)d_in[4];
    const float* bnn = (const float*)d_in[5];
    float* out = (float*)d_out;
    _Float16* fprep = (_Float16*)d_ws;   // 3 * 319488 * 2 B = 1.83 MB

    prep_kernel<<<3 * NC16, 256, 0, stream>>>(f0g, f1g, f2g, fprep);

    const int B = in_sizes[0] / 624;     // 8192
    cin_mfma<<<B / NB, 512, 0, stream>>>(xin, fprep, wnn, bnn, out);
}

// Round 23
// 242.941 us; speedup vs baseline: 1.4796x; 1.4796x over previous
//
#include <hip/hip_runtime.h>

// CIN fused kernel, round 17 (4th resubmit; broker timeouts).
// r16 post-mortem: phase-stagger branch duplicated the K-loop body ->
// spill (VGPR 128, WRITE 309MB, 306us). Reverted to r15 (174us verified).
// r15 residual (3600 cyc/iter vs 2048 MFMA floor): ds_reads serialize with
// MFMA because the compiler has NO spare registers to pipeline Bf one step
// ahead (124/128 VGPR, needs 8). Fix: reclaim the 8-VGPR staging pair by
// switching T14 reg-staging to global_load_lds (zero regs, no ds_write).
// r6-r9's drain failure does NOT apply: r6 drained vmcnt ~256 cyc after
// issue; here panel loads are issued at iteration top and the single
// per-iter __syncthreads drains them after ~2000+ cyc of compute -> free.
// Also drops the second prologue barrier (hreg barrier drains panel 0).
// Everything else byte-identical to r15: NB=32, 512 thr, wave = 2m x 4n,
// acc[2][4]=128 AGPR, hreg resident, premask fprep, literal indices,
// LDS 147.9KB (1 block/CU).

#define F0N 39
#define NB  32                                // batches per block
#define NC16 156                              // K/16 per layer
#define LAYER_HALVES (NC16 * 4 * 64 * 8)      // 319488 f16 per layer
#define IHALFS 8192                           // halfs per i-panel (4 steps x 4nt x 64 x 8)

typedef _Float16 half8 __attribute__((ext_vector_type(8)));
typedef float f32x16 __attribute__((ext_vector_type(16)));

// ---- prep: swizzle filters into 32x32x16 B-fragment order, f16 ----
// fprep[l][c16][nt][lane][reg] = F_l[row(kg), nt*32 + (lane&31)],
// kg = c16*16 + (lane>>5)*8 + reg.
// Layer 0 PREMASKED: row = i*39+j (i=kg>>6, j=kg&63); value = 2*f0[row,n]
// if (j<39 && j>i) else 0 (triu mask + 2.0 scale baked in; verified).
__global__ void prep_kernel(const float* __restrict__ f0,
                            const float* __restrict__ f1,
                            const float* __restrict__ f2,
                            _Float16* __restrict__ fprep) {
    int blk  = blockIdx.x;            // l*NC16 + c16
    int l    = blk / NC16;
    int c16  = blk - l * NC16;
    int t    = threadIdx.x;
    int nt   = t >> 6;
    int lane = t & 63;
    int hf   = lane >> 5;
    int n    = nt * 32 + (lane & 31);
    const float* f = (l == 0) ? f0 : ((l == 1) ? f1 : f2);
    half8 v;
    #pragma unroll
    for (int reg = 0; reg < 8; ++reg) {
        int kg = c16 * 16 + hf * 8 + reg;
        float x;
        if (l == 0) {
            int fi = kg >> 6, fj = kg & 63;
            x = (fj < F0N && fj > fi) ? 2.0f * f[(fi * F0N + fj) * 128 + n] : 0.0f;
        } else {
            x = f[(size_t)kg * 128 + n];
        }
        v[reg] = (_Float16)x;
    }
    *(half8*)&fprep[(size_t)l * LAYER_HALVES + (((c16 * 4 + nt) * 64 + lane) << 3)] = v;
}

// One K=16 step (Q literal): Bf from LDS (lane-contiguous 16B, conflict-
// free), resident hreg, 8 MFMAs.
#define FULL_STEP_LS(Q)                                                       \
    do {                                                                      \
        half8 Bf[4];                                                          \
        _Pragma("unroll")                                                     \
        for (int nt = 0; nt < 4; ++nt)                                        \
            Bf[nt] = *(const half8*)&bcur[(((Q) * 4 + nt) * 64 + lane) << 3]; \
        half8 Af[2];                                                          \
        _Pragma("unroll")                                                     \
        for (int mt = 0; mt < 2; ++mt) Af[mt] = hreg[mt][(Q)] * xv2[mt];      \
        _Pragma("unroll")                                                     \
        for (int mt = 0; mt < 2; ++mt)                                        \
            _Pragma("unroll")                                                 \
            for (int nt = 0; nt < 4; ++nt)                                    \
                acc[mt][nt] = __builtin_amdgcn_mfma_f32_32x32x16_f16(         \
                    Af[mt], Bf[nt], acc[mt][nt], 0, 0, 0);                    \
    } while (0)

// stage panel IP into LDS buffer via global_load_lds (no VGPRs).
// 512 thr x 2 x 16B = 16KB panel. LDS dest = wave-uniform base + lane*16.
#define STAGE_GLDS(IP, BUFP)                                                  \
    do {                                                                      \
        const _Float16* gsrc = fpl + (size_t)(IP) * IHALFS + (t << 3);        \
        __builtin_amdgcn_global_load_lds(                                     \
            (const __attribute__((address_space(1))) void*)gsrc,              \
            (__attribute__((address_space(3))) void*)&(BUFP)[t << 3],         \
            16, 0, 0);                                                        \
        __builtin_amdgcn_global_load_lds(                                     \
            (const __attribute__((address_space(1))) void*)(gsrc + 4096),     \
            (__attribute__((address_space(3))) void*)&(BUFP)[4096 + (t << 3)],\
            16, 0, 0);                                                        \
    } while (0)

__global__ __launch_bounds__(512, 2) void cin_mfma(
    const float* __restrict__ xin,     // (B, 624) fp32
    const _Float16* __restrict__ fprep,
    const float* __restrict__ wnn,     // (256)
    const float* __restrict__ bnn,     // (1)
    float* __restrict__ out)           // (B)
{
    __shared__ _Float16 hT[NB * 16 * 72] __attribute__((aligned(16)));  // [nb][d][j pad72]
    __shared__ _Float16 xs[NB * 16 * 40] __attribute__((aligned(16)));  // [nb][d][i pad40]
    __shared__ _Float16 bst[2][IHALFS] __attribute__((aligned(16)));    // B i-panel dbuf
    __shared__ float outacc[NB];

    const int t     = threadIdx.x;
    const int wave  = t >> 6;
    const int lane  = t & 63;
    const int hf    = lane >> 5;     // k-half within 16-chunk
    const int lane5 = lane & 31;
    const int dl    = lane & 15;     // d for A-side
    const int bt    = lane5 >> 4;    // A-side batch within 32-row tile
    const int wb0   = wave * 4;      // wave's first batch (local, 0..28)
    const int b0    = blockIdx.x * NB;

    // zero hT (j-pad must be 0: layer-0 h-runs read j up to 63)
    for (int u = t; u < NB * 16 * 72 / 8; u += 512) ((uint4*)hT)[u] = uint4{0, 0, 0, 0};
    if (t < NB) outacc[t] = 0.0f;
    __syncthreads();

    // stage x0 -> hT (layer-0 hidden, [nb][d][j=i]) and xs ([nb][d][i])
    for (int u = t; u < NB * F0N; u += 512) {
        int nb = u / F0N;
        int i  = u - nb * F0N;
        const float* src = xin + (size_t)(b0 + nb) * 624 + i * 16;
        #pragma unroll
        for (int q = 0; q < 4; ++q) {
            float4 v = *(const float4*)(src + q * 4);
            int d = q * 4;
            hT[(nb * 16 + d + 0) * 72 + i] = (_Float16)v.x;
            hT[(nb * 16 + d + 1) * 72 + i] = (_Float16)v.y;
            hT[(nb * 16 + d + 2) * 72 + i] = (_Float16)v.z;
            hT[(nb * 16 + d + 3) * 72 + i] = (_Float16)v.w;
            xs[(nb * 16 + d + 0) * 40 + i] = (_Float16)v.x;
            xs[(nb * 16 + d + 1) * 40 + i] = (_Float16)v.y;
            xs[(nb * 16 + d + 2) * 40 + i] = (_Float16)v.z;
            xs[(nb * 16 + d + 3) * 40 + i] = (_Float16)v.w;
        }
    }
    __syncthreads();

    for (int layer = 0; layer < 3; ++layer) {
        const _Float16* fpl = fprep + (size_t)layer * LAYER_HALVES;

        // prologue: issue panel-0 loads (drained by the hreg barrier below)
        STAGE_GLDS(0, bst[0]);

        // lane's A rows: batch wb0 + mt*2 + bt, d = dl; 4 half8 per batch.
        half8 hreg[2][4];
        #pragma unroll
        for (int mt = 0; mt < 2; ++mt) {
            int base = ((wb0 + mt * 2 + bt) * 16 + dl) * 72 + hf * 8;
            #pragma unroll
            for (int r = 0; r < 4; ++r)
                hreg[mt][r] = *(const half8*)&hT[base + r * 16];
        }
        __syncthreads();   // h-regs loaded; panel 0 drained -> bst[0] ready

        f32x16 acc[2][4];
        #pragma unroll
        for (int mt = 0; mt < 2; ++mt)
            #pragma unroll
            for (int nt = 0; nt < 4; ++nt)
                #pragma unroll
                for (int e = 0; e < 16; ++e) acc[mt][nt][e] = 0.0f;

        const int xrow0 = ((wb0 + bt) * 16 + dl) * 40;
        const int xrow1 = ((wb0 + 2 + bt) * 16 + dl) * 40;

        if (layer == 0) {
            // Premasked sparse: q0 live i<15, q1 live i<31, q2 live i<38,
            // q3 dead (all-zero filter rows, never read). 38 iterations.
            _Float16 xv2[2];
            for (int i = 0; i < 38; ++i) {
                const _Float16* bcur = bst[i & 1];
                _Float16* bnxt = bst[(i & 1) ^ 1];
                if (i < 37) STAGE_GLDS(i + 1, bnxt); // issue at iter top
                xv2[0] = xs[xrow0 + i];
                xv2[1] = xs[xrow1 + i];
                if (i < 15) FULL_STEP_LS(0);
                if (i < 31) FULL_STEP_LS(1);
                FULL_STEP_LS(2);
                __syncthreads();   // drain (loads ~2000cyc old) + buf swap
            }
        } else {
            _Float16 xv2[2];
            for (int i = 0; i < F0N; ++i) {
                const _Float16* bcur = bst[i & 1];
                _Float16* bnxt = bst[(i & 1) ^ 1];
                if (i < F0N - 1) STAGE_GLDS(i + 1, bnxt); // issue at iter top
                xv2[0] = xs[xrow0 + i];
                xv2[1] = xs[xrow1 + i];
                FULL_STEP_LS(0);
                FULL_STEP_LS(1);
                FULL_STEP_LS(2);
                FULL_STEP_LS(3);
                __syncthreads();   // drain + buf swap
            }
        }

        // ---- epilogue ----
        // C/D layout: col n = nt*32 + lane5; row = (reg&3) + 8*(reg>>2) + 4*hf;
        // batch_in_tile = reg>>3, d = (reg&3) + 8*((reg>>2)&1) + 4*hf.
        const int catbase = (layer == 2) ? 128 : ((layer == 0) ? -64 : 0);
        #pragma unroll
        for (int mt = 0; mt < 2; ++mt) {
            const int nb0 = wb0 + mt * 2;
            float cm0 = 0.0f, cm1 = 0.0f;
            #pragma unroll
            for (int nt = 0; nt < 4; ++nt) {
                float r[16];
                #pragma unroll
                for (int reg = 0; reg < 16; ++reg)
                    r[reg] = fmaxf(acc[mt][nt][reg], 0.0f);
                if (layer < 2 && nt < 2) {         // next hidden: cols 0..63
                    const int j = nt * 32 + lane5;
                    #pragma unroll
                    for (int reg = 0; reg < 16; ++reg) {
                        int nb = nb0 + (reg >> 3);
                        int d  = (reg & 3) + 8 * ((reg >> 2) & 1) + 4 * hf;
                        hT[(nb * 16 + d) * 72 + j] = (_Float16)r[reg];
                    }
                }
                if (layer == 2 || nt >= 2) {       // direct-out readout
                    const float w = 1.0f + wnn[catbase + nt * 32 + lane5];
                    float s0r = ((r[0] + r[1]) + (r[2] + r[3])) +
                                ((r[4] + r[5]) + (r[6] + r[7]));
                    float s1r = ((r[8] + r[9]) + (r[10] + r[11])) +
                                ((r[12] + r[13]) + (r[14] + r[15]));
                    s0r += __shfl_xor(s0r, 32, 64);  // combine hf halves
                    s1r += __shfl_xor(s1r, 32, 64);
                    cm0 = fmaf(s0r, w, cm0);
                    cm1 = fmaf(s1r, w, cm1);
                }
            }
            #pragma unroll
            for (int sh = 16; sh >= 1; sh >>= 1) {
                cm0 += __shfl_xor(cm0, sh, 64);
                cm1 += __shfl_xor(cm1, sh, 64);
            }
            if (lane == 0) {
                atomicAdd(&outacc[nb0], cm0);
                atomicAdd(&outacc[nb0 + 1], cm1);
            }
        }
        __syncthreads();   // hT(next hidden) + outacc visible
    }

    if (t < NB) out[b0 + t] = outacc[t] + bnn[0];
}

extern "C" void kernel_launch(void* const* d_in, const int* in_sizes, int n_in,
                              void* d_out, int out_size, void* d_ws, size_t ws_size,
                              hipStream_t stream) {
    const float* xin = (const float*)d_in[0];
    const float* f0g = (const float*)d_in[1];
    const float* f1g = (const float*)d_in[2];
    const float* f2g = (const float*)d_in[3];
    const float* wnn = (const float*)d_in[4];
    const float* bnn = (const float*)d_in[5];
    float* out = (float*)d_out;
    _Float16* fprep = (_Float16*)d_ws;   // 3 * 319488 * 2 B = 1.83 MB

    prep_kernel<<<3 * NC16, 256, 0, stream>>>(f0g, f1g, f2g, fprep);

    const int B = in_sizes[0] / 624;     // 8192
    cin_mfma<<<B / NB, 512, 0, stream>>>(xin, fprep, wnn, bnn, out);
}

// Round 24
// 237.977 us; speedup vs baseline: 1.5105x; 1.0209x over previous
//
#include <hip/hip_runtime.h>

// CIN fused kernel, round 18: REVERT to r15 (verified best: 174us dispatch,
// 238us bench, MfmaUtil 57.5%, WRITE 32B, VGPR 124).
// r17 post-mortem (193us, MfmaUtil 48%, VGPR unchanged 124): the register-
// headroom theory was REFUTED -- removing the 8-VGPR staging pair freed
// nothing (allocator budget binds elsewhere), and global_load_lds REGRESSED:
// its LDS writes land at data-return time, contending with the compute
// phase's ds_read_b128 bursts; r15's batched STAGE_WRITE (between steps 2
// and 3) dodges that window, and its per-wave s_waitcnt lets waves proceed
// independently instead of draining at the all-thread barrier.
// Refutation ledger at this geometry: occupancy-up spills (r11/r14);
// wave-stagger spills (r16); barrier-free streaming is L1-BW-bound
// (r10-r13); counted-vmcnt spills (r8/r9); global_load_lds staging
// regresses (r17). The residual gap to the ~94us MFMA floor requires
// pipelining registers that don't exist at 252/256 unified regs --
// structural to the 2m x 4n / acc[2][4] tile.
// Structure: T14 reg-staging (issue-early/write-late), one __syncthreads
// per i-iter (zero drain), NB=32, 512 thr, wave = 2m x 4n, acc[2][4] =
// 128 AGPR, hreg[2][4] resident, premask fprep, literal indices,
// LDS 147.9KB (1 block/CU).

#define F0N 39
#define NB  32                                // batches per block
#define NC16 156                              // K/16 per layer
#define LAYER_HALVES (NC16 * 4 * 64 * 8)      // 319488 f16 per layer
#define IHALFS 8192                           // halfs per i-panel (4 steps x 4nt x 64 x 8)

typedef _Float16 half8 __attribute__((ext_vector_type(8)));
typedef float f32x16 __attribute__((ext_vector_type(16)));

// ---- prep: swizzle filters into 32x32x16 B-fragment order, f16 ----
// fprep[l][c16][nt][lane][reg] = F_l[row(kg), nt*32 + (lane&31)],
// kg = c16*16 + (lane>>5)*8 + reg.
// Layer 0 PREMASKED: row = i*39+j (i=kg>>6, j=kg&63); value = 2*f0[row,n]
// if (j<39 && j>i) else 0 (triu mask + 2.0 scale baked in; verified).
__global__ void prep_kernel(const float* __restrict__ f0,
                            const float* __restrict__ f1,
                            const float* __restrict__ f2,
                            _Float16* __restrict__ fprep) {
    int blk  = blockIdx.x;            // l*NC16 + c16
    int l    = blk / NC16;
    int c16  = blk - l * NC16;
    int t    = threadIdx.x;
    int nt   = t >> 6;
    int lane = t & 63;
    int hf   = lane >> 5;
    int n    = nt * 32 + (lane & 31);
    const float* f = (l == 0) ? f0 : ((l == 1) ? f1 : f2);
    half8 v;
    #pragma unroll
    for (int reg = 0; reg < 8; ++reg) {
        int kg = c16 * 16 + hf * 8 + reg;
        float x;
        if (l == 0) {
            int fi = kg >> 6, fj = kg & 63;
            x = (fj < F0N && fj > fi) ? 2.0f * f[(fi * F0N + fj) * 128 + n] : 0.0f;
        } else {
            x = f[(size_t)kg * 128 + n];
        }
        v[reg] = (_Float16)x;
    }
    *(half8*)&fprep[(size_t)l * LAYER_HALVES + (((c16 * 4 + nt) * 64 + lane) << 3)] = v;
}

// One K=16 step (Q literal): Bf from LDS (lane-contiguous 16B, conflict-
// free), resident hreg, 8 MFMAs.
#define FULL_STEP_LS(Q)                                                       \
    do {                                                                      \
        half8 Bf[4];                                                          \
        _Pragma("unroll")                                                     \
        for (int nt = 0; nt < 4; ++nt)                                        \
            Bf[nt] = *(const half8*)&bcur[(((Q) * 4 + nt) * 64 + lane) << 3]; \
        half8 Af[2];                                                          \
        _Pragma("unroll")                                                     \
        for (int mt = 0; mt < 2; ++mt) Af[mt] = hreg[mt][(Q)] * xv2[mt];      \
        _Pragma("unroll")                                                     \
        for (int mt = 0; mt < 2; ++mt)                                        \
            _Pragma("unroll")                                                 \
            for (int nt = 0; nt < 4; ++nt)                                    \
                acc[mt][nt] = __builtin_amdgcn_mfma_f32_32x32x16_f16(         \
                    Af[mt], Bf[nt], acc[mt][nt], 0, 0, 0);                    \
    } while (0)

// issue global loads of panel IP into registers (consumed by STAGE_WRITE)
#define STAGE_LOAD(IP)                                                        \
    do {                                                                      \
        const uint4* g = (const uint4*)(fpl + (size_t)(IP) * IHALFS);         \
        s0 = g[t];                                                            \
        s1 = g[t + 512];                                                      \
    } while (0)

// write staged registers into LDS buffer (lane-contiguous 16B, no conflict)
#define STAGE_WRITE(BUFP)                                                     \
    do {                                                                      \
        ((uint4*)(BUFP))[t]       = s0;                                       \
        ((uint4*)(BUFP))[t + 512] = s1;                                       \
    } while (0)

__global__ __launch_bounds__(512, 2) void cin_mfma(
    const float* __restrict__ xin,     // (B, 624) fp32
    const _Float16* __restrict__ fprep,
    const float* __restrict__ wnn,     // (256)
    const float* __restrict__ bnn,     // (1)
    float* __restrict__ out)           // (B)
{
    __shared__ _Float16 hT[NB * 16 * 72] __attribute__((aligned(16)));  // [nb][d][j pad72]
    __shared__ _Float16 xs[NB * 16 * 40] __attribute__((aligned(16)));  // [nb][d][i pad40]
    __shared__ _Float16 bst[2][IHALFS] __attribute__((aligned(16)));    // B i-panel dbuf
    __shared__ float outacc[NB];

    const int t     = threadIdx.x;
    const int wave  = t >> 6;
    const int lane  = t & 63;
    const int hf    = lane >> 5;     // k-half within 16-chunk
    const int lane5 = lane & 31;
    const int dl    = lane & 15;     // d for A-side
    const int bt    = lane5 >> 4;    // A-side batch within 32-row tile
    const int wb0   = wave * 4;      // wave's first batch (local, 0..28)
    const int b0    = blockIdx.x * NB;

    // zero hT (j-pad must be 0: layer-0 h-runs read j up to 63)
    for (int u = t; u < NB * 16 * 72 / 8; u += 512) ((uint4*)hT)[u] = uint4{0, 0, 0, 0};
    if (t < NB) outacc[t] = 0.0f;
    __syncthreads();

    // stage x0 -> hT (layer-0 hidden, [nb][d][j=i]) and xs ([nb][d][i])
    for (int u = t; u < NB * F0N; u += 512) {
        int nb = u / F0N;
        int i  = u - nb * F0N;
        const float* src = xin + (size_t)(b0 + nb) * 624 + i * 16;
        #pragma unroll
        for (int q = 0; q < 4; ++q) {
            float4 v = *(const float4*)(src + q * 4);
            int d = q * 4;
            hT[(nb * 16 + d + 0) * 72 + i] = (_Float16)v.x;
            hT[(nb * 16 + d + 1) * 72 + i] = (_Float16)v.y;
            hT[(nb * 16 + d + 2) * 72 + i] = (_Float16)v.z;
            hT[(nb * 16 + d + 3) * 72 + i] = (_Float16)v.w;
            xs[(nb * 16 + d + 0) * 40 + i] = (_Float16)v.x;
            xs[(nb * 16 + d + 1) * 40 + i] = (_Float16)v.y;
            xs[(nb * 16 + d + 2) * 40 + i] = (_Float16)v.z;
            xs[(nb * 16 + d + 3) * 40 + i] = (_Float16)v.w;
        }
    }
    __syncthreads();

    for (int layer = 0; layer < 3; ++layer) {
        const _Float16* fpl = fprep + (size_t)layer * LAYER_HALVES;
        uint4 s0, s1;

        // prologue: issue panel-0 loads (overlap with hreg ds_reads)
        STAGE_LOAD(0);

        // lane's A rows: batch wb0 + mt*2 + bt, d = dl; 4 half8 per batch.
        half8 hreg[2][4];
        #pragma unroll
        for (int mt = 0; mt < 2; ++mt) {
            int base = ((wb0 + mt * 2 + bt) * 16 + dl) * 72 + hf * 8;
            #pragma unroll
            for (int r = 0; r < 4; ++r)
                hreg[mt][r] = *(const half8*)&hT[base + r * 16];
        }
        __syncthreads();   // h-regs loaded (epilogue of prev layer done)

        STAGE_WRITE(bst[0]);   // panel 0 -> buf0 (waits its loads)
        __syncthreads();       // buf0 visible to all waves

        f32x16 acc[2][4];
        #pragma unroll
        for (int mt = 0; mt < 2; ++mt)
            #pragma unroll
            for (int nt = 0; nt < 4; ++nt)
                #pragma unroll
                for (int e = 0; e < 16; ++e) acc[mt][nt][e] = 0.0f;

        const int xrow0 = ((wb0 + bt) * 16 + dl) * 40;
        const int xrow1 = ((wb0 + 2 + bt) * 16 + dl) * 40;

        if (layer == 0) {
            // Premasked sparse: q0 live i<15, q1 live i<31, q2 live i<38,
            // q3 dead (all-zero filter rows, never read). 38 iterations.
            _Float16 xv2[2];
            for (int i = 0; i < 38; ++i) {
                const _Float16* bcur = bst[i & 1];
                _Float16* bnxt = bst[(i & 1) ^ 1];
                if (i < 37) STAGE_LOAD(i + 1);      // issue early
                xv2[0] = xs[xrow0 + i];
                xv2[1] = xs[xrow1 + i];
                if (i < 15) FULL_STEP_LS(0);
                if (i < 31) FULL_STEP_LS(1);
                if (i < 37) STAGE_WRITE(bnxt);      // write late (loads landed)
                FULL_STEP_LS(2);
                __syncthreads();                    // buf swap; zero drain
            }
        } else {
            _Float16 xv2[2];
            for (int i = 0; i < F0N; ++i) {
                const _Float16* bcur = bst[i & 1];
                _Float16* bnxt = bst[(i & 1) ^ 1];
                if (i < F0N - 1) STAGE_LOAD(i + 1); // issue early
                xv2[0] = xs[xrow0 + i];
                xv2[1] = xs[xrow1 + i];
                FULL_STEP_LS(0);
                FULL_STEP_LS(1);
                FULL_STEP_LS(2);
                if (i < F0N - 1) STAGE_WRITE(bnxt); // write late (loads landed)
                FULL_STEP_LS(3);
                __syncthreads();                    // buf swap; zero drain
            }
        }

        // ---- epilogue ----
        // C/D layout: col n = nt*32 + lane5; row = (reg&3) + 8*(reg>>2) + 4*hf;
        // batch_in_tile = reg>>3, d = (reg&3) + 8*((reg>>2)&1) + 4*hf.
        const int catbase = (layer == 2) ? 128 : ((layer == 0) ? -64 : 0);
        #pragma unroll
        for (int mt = 0; mt < 2; ++mt) {
            const int nb0 = wb0 + mt * 2;
            float cm0 = 0.0f, cm1 = 0.0f;
            #pragma unroll
            for (int nt = 0; nt < 4; ++nt) {
                float r[16];
                #pragma unroll
                for (int reg = 0; reg < 16; ++reg)
                    r[reg] = fmaxf(acc[mt][nt][reg], 0.0f);
                if (layer < 2 && nt < 2) {         // next hidden: cols 0..63
                    const int j = nt * 32 + lane5;
                    #pragma unroll
                    for (int reg = 0; reg < 16; ++reg) {
                        int nb = nb0 + (reg >> 3);
                        int d  = (reg & 3) + 8 * ((reg >> 2) & 1) + 4 * hf;
                        hT[(nb * 16 + d) * 72 + j] = (_Float16)r[reg];
                    }
                }
                if (layer == 2 || nt >= 2) {       // direct-out readout
                    const float w = 1.0f + wnn[catbase + nt * 32 + lane5];
                    float s0r = ((r[0] + r[1]) + (r[2] + r[3])) +
                                ((r[4] + r[5]) + (r[6] + r[7]));
                    float s1r = ((r[8] + r[9]) + (r[10] + r[11])) +
                                ((r[12] + r[13]) + (r[14] + r[15]));
                    s0r += __shfl_xor(s0r, 32, 64);  // combine hf halves
                    s1r += __shfl_xor(s1r, 32, 64);
                    cm0 = fmaf(s0r, w, cm0);
                    cm1 = fmaf(s1r, w, cm1);
                }
            }
            #pragma unroll
            for (int sh = 16; sh >= 1; sh >>= 1) {
                cm0 += __shfl_xor(cm0, sh, 64);
                cm1 += __shfl_xor(cm1, sh, 64);
            }
            if (lane == 0) {
                atomicAdd(&outacc[nb0], cm0);
                atomicAdd(&outacc[nb0 + 1], cm1);
            }
        }
        __syncthreads();   // hT(next hidden) + outacc visible
    }

    if (t < NB) out[b0 + t] = outacc[t] + bnn[0];
}

extern "C" void kernel_launch(void* const* d_in, const int* in_sizes, int n_in,
                              void* d_out, int out_size, void* d_ws, size_t ws_size,
                              hipStream_t stream) {
    const float* xin = (const float*)d_in[0];
    const float* f0g = (const float*)d_in[1];
    const float* f1g = (const float*)d_in[2];
    const float* f2g = (const float*)d_in[3];
    const float* wnn = (const float*)d_in[4];
    const float* bnn = (const float*)d_in[5];
    float* out = (float*)d_out;
    _Float16* fprep = (_Float16*)d_ws;   // 3 * 319488 * 2 B = 1.83 MB

    prep_kernel<<<3 * NC16, 256, 0, stream>>>(f0g, f1g, f2g, fprep);

    const int B = in_sizes[0] / 624;     // 8192
    cin_mfma<<<B / NB, 512, 0, stream>>>(xin, fprep, wnn, bnn, out);
}